// Round 1
// baseline (267.795 us; speedup 1.0000x reference)
//
#include <hip/hip_runtime.h>
#include <hip/hip_bf16.h>
#include <cstddef>
#include <cstdint>

// Problem sizes (fixed)
#define B_ 16
#define H_ 512
#define N_ 2048
#define DN_ 256
#define G_ 64

typedef __attribute__((ext_vector_type(8))) short short8;
typedef __attribute__((ext_vector_type(4))) float f32x4;

// ---------------- workspace layout (bytes) ----------------
static constexpr size_t OFF_Q      = 0;                          // 16*64 f32
static constexpr size_t OFF_K      = 4096;                       // 2048*64 f32
static constexpr size_t OFF_V      = OFF_K + (size_t)N_*G_*4;    // 2048*64 f32
static constexpr size_t OFF_ALPHA  = OFF_V + (size_t)N_*G_*4;    // 16*2048 f32
static constexpr size_t OFF_DIS    = OFF_ALPHA + (size_t)B_*N_*4;
static constexpr size_t OFF_ROWSUM = OFF_DIS + (size_t)B_*N_*4;  // 2048 f32
static constexpr size_t OFF_ABF    = OFF_ROWSUM + 8192;          // 2048*2048 bf16
static constexpr size_t OFF_VPT    = OFF_ABF + (size_t)N_*N_*2;  // 1024*2048 bf16
static constexpr size_t OFF_S      = OFF_VPT + (size_t)(B_*G_)*N_*2; // 2048*1024 f32

// ---------------- K1: q = h_t @ Wq.T + bq ----------------
__global__ __launch_bounds__(64) void q_kernel(const float* __restrict__ h_t,
                                               const float* __restrict__ Wq,
                                               const float* __restrict__ bq,
                                               float* __restrict__ q) {
    int b = blockIdx.x, g = threadIdx.x;
    __shared__ float hs[H_];
    for (int i = g; i < H_; i += 64) hs[i] = h_t[b * H_ + i];
    __syncthreads();
    float acc = bq[g];
    for (int h = 0; h < H_; h++) acc = fmaf(hs[h], Wq[g * H_ + h], acc);
    q[b * G_ + g] = acc;
}

// ---------------- K2: k,v = node_repr @ {Wk,Wv}.T + b ----------------
__global__ __launch_bounds__(64) void kv_kernel(const float* __restrict__ node_repr,
                                                const float* __restrict__ Wk,
                                                const float* __restrict__ bk,
                                                const float* __restrict__ Wv,
                                                const float* __restrict__ bv,
                                                float* __restrict__ k,
                                                float* __restrict__ v) {
    int n = blockIdx.x, g = threadIdx.x;
    __shared__ float xs[DN_];
    for (int i = g; i < DN_; i += 64) xs[i] = node_repr[(size_t)n * DN_ + i];
    __syncthreads();
    float kk = bk[g], vv = bv[g];
    for (int d = 0; d < DN_; d++) {
        float x = xs[d];
        kk = fmaf(x, Wk[g * DN_ + d], kk);
        vv = fmaf(x, Wv[g * DN_ + d], vv);
    }
    k[(size_t)n * G_ + g] = kk;
    v[(size_t)n * G_ + g] = vv;
}

// ---------------- K3: rowsum(base_adj) + bf16 cast ----------------
__global__ __launch_bounds__(256) void rowsum_cast_kernel(const float* __restrict__ base_adj,
                                                          __hip_bfloat16* __restrict__ Abf,
                                                          float* __restrict__ rowsum) {
    __shared__ float red[4];
    int n = blockIdx.x, tid = threadIdx.x;
    float s = 0.f;
    for (int m = tid; m < N_; m += 256) {
        float x = base_adj[(size_t)n * N_ + m];
        s += x;
        Abf[(size_t)n * N_ + m] = __float2bfloat16(x);
    }
    #pragma unroll
    for (int off = 32; off; off >>= 1) s += __shfl_xor(s, off, 64);
    if ((tid & 63) == 0) red[tid >> 6] = s;
    __syncthreads();
    if (tid == 0) rowsum[n] = red[0] + red[1] + red[2] + red[3];
}

// ---------------- K4: softmax over n, alpha + d_inv_sqrt ----------------
__global__ __launch_bounds__(1024) void softmax_kernel(const float* __restrict__ q,
                                                       const float* __restrict__ k,
                                                       const float* __restrict__ rowsum,
                                                       float* __restrict__ alpha,
                                                       float* __restrict__ dis) {
    __shared__ float qs[G_];
    __shared__ float red[16];
    __shared__ float bval;
    int b = blockIdx.x, tid = threadIdx.x;
    if (tid < G_) qs[tid] = q[b * G_ + tid];
    __syncthreads();
    int n1 = tid, n2 = tid + 1024;
    float l1 = 0.f, l2 = 0.f;
    for (int g = 0; g < G_; g++) {
        float qq = qs[g];
        l1 = fmaf(qq, k[(size_t)n1 * G_ + g], l1);
        l2 = fmaf(qq, k[(size_t)n2 * G_ + g], l2);
    }
    l1 *= 0.125f; l2 *= 0.125f;
    // block max
    float m = fmaxf(l1, l2);
    #pragma unroll
    for (int off = 32; off; off >>= 1) m = fmaxf(m, __shfl_xor(m, off, 64));
    if ((tid & 63) == 0) red[tid >> 6] = m;
    __syncthreads();
    if (tid < 16) {
        float x = red[tid];
        #pragma unroll
        for (int off = 8; off; off >>= 1) x = fmaxf(x, __shfl_xor(x, off, 16));
        if (tid == 0) bval = x;
    }
    __syncthreads();
    m = bval;
    __syncthreads();
    float e1 = expf(l1 - m), e2 = expf(l2 - m);
    // block sum
    float s = e1 + e2;
    #pragma unroll
    for (int off = 32; off; off >>= 1) s += __shfl_xor(s, off, 64);
    if ((tid & 63) == 0) red[tid >> 6] = s;
    __syncthreads();
    if (tid < 16) {
        float x = red[tid];
        #pragma unroll
        for (int off = 8; off; off >>= 1) x += __shfl_xor(x, off, 16);
        if (tid == 0) bval = x;
    }
    __syncthreads();
    float inv = 1.f / bval;
    float a1 = e1 * inv, a2 = e2 * inv;
    alpha[(size_t)b * N_ + n1] = a1;
    alpha[(size_t)b * N_ + n2] = a2;
    dis[(size_t)b * N_ + n1] = rsqrtf(fmaf(a1, rowsum[n1], 1.f + 1e-8f));
    dis[(size_t)b * N_ + n2] = rsqrtf(fmaf(a2, rowsum[n2], 1.f + 1e-8f));
}

// ---------------- K5: VpT[c][m] = bf16(dis[b,m] * v[m,g]), c = b*64+g ----------------
__global__ __launch_bounds__(256) void vpt_kernel(const float* __restrict__ v,
                                                  const float* __restrict__ dis,
                                                  __hip_bfloat16* __restrict__ VpT) {
    size_t id = (size_t)blockIdx.x * 256 + threadIdx.x; // 0 .. 1024*2048-1
    int c = (int)(id >> 11);
    int m = (int)(id & 2047);
    int b = c >> 6, g = c & 63;
    float val = dis[(size_t)b * N_ + m] * v[(size_t)m * G_ + g];
    VpT[(size_t)c * N_ + m] = __float2bfloat16(val);
}

// ---------------- K6: S = Abf @ VpT^T   (MFMA bf16) ----------------
// S[row, col] = sum_k Abf[row][k] * VpT[col][k];  M=2048, Ncols=1024, K=2048
#define BM 128
#define BN 64
#define BK 32
__global__ __launch_bounds__(256) void gemm_S(const __hip_bfloat16* __restrict__ Abf,
                                              const __hip_bfloat16* __restrict__ VpT,
                                              float* __restrict__ S) {
    __shared__ __align__(16) short A_lds[BM * BK]; // [row][k]
    __shared__ __align__(16) short B_lds[BN * BK]; // [col][k]
    const int tid = threadIdx.x;
    const int n0 = blockIdx.x * BM;
    const int c0 = blockIdx.y * BN;
    const int wave = tid >> 6, l = tid & 63;
    const int wr = wave >> 1, wc = wave & 1;
    const int lr = l & 15, kg = l >> 4;

    f32x4 acc[4][2];
    #pragma unroll
    for (int m = 0; m < 4; m++)
        #pragma unroll
        for (int n = 0; n < 2; n++) acc[m][n] = (f32x4){0.f, 0.f, 0.f, 0.f};

    const int row_s = tid >> 2;          // staging row for this thread
    const int kc_s  = (tid & 3) << 3;    // staging k-offset (8 elems)

    for (int k0 = 0; k0 < N_; k0 += BK) {
        // stage A tile: 128x32 bf16, 2 rounds of 256 threads x 16B
        #pragma unroll
        for (int r = 0; r < 2; r++) {
            int idx = r * 256 + tid;
            int row = idx >> 2;
            int kc = (idx & 3) << 3;
            *(short8*)&A_lds[idx * 8] =
                *(const short8*)&Abf[(size_t)(n0 + row) * N_ + k0 + kc];
        }
        // stage B tile: 64x32 bf16, 1 round
        *(short8*)&B_lds[tid * 8] =
            *(const short8*)&VpT[(size_t)(c0 + row_s) * N_ + k0 + kc_s];
        __syncthreads();

        short8 a[4], bfr[2];
        #pragma unroll
        for (int m = 0; m < 4; m++)
            a[m] = *(const short8*)&A_lds[(wr * 64 + m * 16 + lr) * BK + kg * 8];
        #pragma unroll
        for (int n = 0; n < 2; n++)
            bfr[n] = *(const short8*)&B_lds[(wc * 32 + n * 16 + lr) * BK + kg * 8];
        #pragma unroll
        for (int m = 0; m < 4; m++)
            #pragma unroll
            for (int n = 0; n < 2; n++)
                acc[m][n] = __builtin_amdgcn_mfma_f32_16x16x32_bf16(a[m], bfr[n], acc[m][n], 0, 0, 0);
        __syncthreads();
    }
    // epilogue: C/D layout col=lane&15, row=(lane>>4)*4+reg
    #pragma unroll
    for (int m = 0; m < 4; m++)
        #pragma unroll
        for (int n = 0; n < 2; n++)
            #pragma unroll
            for (int r = 0; r < 4; r++) {
                int row = n0 + wr * 64 + m * 16 + kg * 4 + r;
                int col = c0 + wc * 32 + n * 16 + lr;
                S[(size_t)row * (B_ * G_) + col] = acc[m][n][r];
            }
}

// ---------------- K7: z -> Wo -> ReLU -> LayerNorm -> updated_nodes ----------------
__global__ __launch_bounds__(256) void epilogue_kernel(const float* __restrict__ S,
                                                       const float* __restrict__ v,
                                                       const float* __restrict__ alpha,
                                                       const float* __restrict__ dis,
                                                       const float* __restrict__ Wo,
                                                       const float* __restrict__ bo,
                                                       const float* __restrict__ gamma,
                                                       const float* __restrict__ beta,
                                                       float* __restrict__ un) {
    __shared__ float WoT[G_ * G_];   // WoT[g][g2] = Wo[g2][g]
    __shared__ float zbuf[4][G_];
    __shared__ float cvec[3 * G_];   // bo, gamma, beta
    const int tid = threadIdx.x;
    const int b = blockIdx.y;
    const int nbase = blockIdx.x * 32;
    for (int i = tid; i < G_ * G_; i += 256) {
        int g = i >> 6, g2 = i & 63;
        WoT[i] = Wo[g2 * G_ + g];
    }
    if (tid < G_) {
        cvec[tid] = bo[tid];
        cvec[G_ + tid] = gamma[tid];
        cvec[2 * G_ + tid] = beta[tid];
    }
    __syncthreads();
    const int wave = tid >> 6, lane = tid & 63;
    for (int i = 0; i < 8; i++) {
        int n = nbase + i * 4 + wave;
        float al = alpha[(size_t)b * N_ + n];
        float di = dis[(size_t)b * N_ + n];
        float zp = di * fmaf(al, S[(size_t)n * (B_ * G_) + b * G_ + lane],
                             di * v[(size_t)n * G_ + lane]);
        zbuf[wave][lane] = zp;
        __syncthreads();
        float y = cvec[lane];
        #pragma unroll
        for (int g = 0; g < G_; g++) y = fmaf(zbuf[wave][g], WoT[g * G_ + lane], y);
        y = fmaxf(y, 0.f);
        // LayerNorm over the 64 lanes of this wave
        float s = y;
        #pragma unroll
        for (int off = 32; off; off >>= 1) s += __shfl_xor(s, off, 64);
        float mu = s * (1.f / 64.f);
        float d0 = y - mu;
        float s2 = d0 * d0;
        #pragma unroll
        for (int off = 32; off; off >>= 1) s2 += __shfl_xor(s2, off, 64);
        float rstd = rsqrtf(s2 * (1.f / 64.f) + 1e-5f);
        float outv = fmaf(d0 * rstd, cvec[G_ + lane], cvec[2 * G_ + lane]);
        un[((size_t)b * N_ + n) * G_ + lane] = outv;
        __syncthreads();
    }
}

// ---------------- K8: relation_vector + propagated_summary ----------------
__global__ __launch_bounds__(256) void summary_kernel(const float* __restrict__ alpha,
                                                      const float* __restrict__ v,
                                                      const float* __restrict__ un,
                                                      float* __restrict__ out) {
    __shared__ float part[256];
    int b = blockIdx.x, which = blockIdx.y; // 0 -> relation_vector, 1 -> propagated_summary
    int g = threadIdx.x & 63, c = threadIdx.x >> 6;
    float acc = 0.f;
    if (which == 0) {
        for (int n = c; n < N_; n += 4)
            acc = fmaf(alpha[(size_t)b * N_ + n], v[(size_t)n * G_ + g], acc);
    } else {
        for (int n = c; n < N_; n += 4)
            acc = fmaf(alpha[(size_t)b * N_ + n], un[((size_t)b * N_ + n) * G_ + g], acc);
    }
    part[threadIdx.x] = acc;
    __syncthreads();
    if (c == 0) {
        float s = part[g] + part[64 + g] + part[128 + g] + part[192 + g];
        if (which == 0) out[1024 + b * G_ + g] = s;       // relation_vector
        else            out[b * G_ + g] = s;               // propagated_summary
    }
}

extern "C" void kernel_launch(void* const* d_in, const int* in_sizes, int n_in,
                              void* d_out, int out_size, void* d_ws, size_t ws_size,
                              hipStream_t stream) {
    const float* h_t       = (const float*)d_in[0];
    const float* node_repr = (const float*)d_in[1];
    const float* base_adj  = (const float*)d_in[2];
    const float* Wq    = (const float*)d_in[3];
    const float* bq    = (const float*)d_in[4];
    const float* Wk    = (const float*)d_in[5];
    const float* bk    = (const float*)d_in[6];
    const float* Wv    = (const float*)d_in[7];
    const float* bv    = (const float*)d_in[8];
    const float* Wo    = (const float*)d_in[9];
    const float* bo    = (const float*)d_in[10];
    const float* gamma = (const float*)d_in[11];
    const float* beta  = (const float*)d_in[12];
    float* out = (float*)d_out;

    char* ws = (char*)d_ws;
    float* q      = (float*)(ws + OFF_Q);
    float* k      = (float*)(ws + OFF_K);
    float* v      = (float*)(ws + OFF_V);
    float* alpha  = (float*)(ws + OFF_ALPHA);
    float* dis    = (float*)(ws + OFF_DIS);
    float* rowsum = (float*)(ws + OFF_ROWSUM);
    __hip_bfloat16* Abf = (__hip_bfloat16*)(ws + OFF_ABF);
    __hip_bfloat16* VpT = (__hip_bfloat16*)(ws + OFF_VPT);
    float* S      = (float*)(ws + OFF_S);

    float* un = out + 2048; // updated_nodes region

    q_kernel<<<B_, 64, 0, stream>>>(h_t, Wq, bq, q);
    kv_kernel<<<N_, 64, 0, stream>>>(node_repr, Wk, bk, Wv, bv, k, v);
    rowsum_cast_kernel<<<N_, 256, 0, stream>>>(base_adj, Abf, rowsum);
    softmax_kernel<<<B_, 1024, 0, stream>>>(q, k, rowsum, alpha, dis);
    vpt_kernel<<<(B_ * G_ * N_) / 256, 256, 0, stream>>>(v, dis, VpT);
    gemm_S<<<dim3(N_ / BM, (B_ * G_) / BN), 256, 0, stream>>>(Abf, VpT, S);
    epilogue_kernel<<<dim3(N_ / 32, B_), 256, 0, stream>>>(S, v, alpha, dis, Wo, bo, gamma, beta, un);
    summary_kernel<<<dim3(B_, 2), 256, 0, stream>>>(alpha, v, un, out);
}

// Round 3
// 154.219 us; speedup vs baseline: 1.7365x; 1.7365x over previous
//
#include <hip/hip_runtime.h>
#include <hip/hip_bf16.h>
#include <cstddef>
#include <cstdint>

// Problem sizes (fixed)
#define B_ 16
#define H_ 512
#define N_ 2048
#define DN_ 256
#define G_ 64

typedef __attribute__((ext_vector_type(8))) short short8;
typedef __attribute__((ext_vector_type(4))) short s16x4;
typedef __attribute__((ext_vector_type(4))) float f32x4;

__device__ __forceinline__ unsigned short f2bf(float x) {
    __hip_bfloat16 b = __float2bfloat16(x);
    return *(unsigned short*)&b;
}

// async global->LDS, 16B per lane. LDS dest = wave-uniform base + lane*16.
__device__ __forceinline__ void gl_lds16(const void* g, void* l) {
    __builtin_amdgcn_global_load_lds(
        (const __attribute__((address_space(1))) unsigned int*)g,
        (__attribute__((address_space(3))) unsigned int*)l, 16, 0, 0);
}

// ---------------- workspace layout (bytes) ----------------
static constexpr size_t OFF_Q      = 0;                          // 16*64 f32
static constexpr size_t OFF_K      = 4096;                       // 2048*64 f32
static constexpr size_t OFF_V      = OFF_K + (size_t)N_*G_*4;    // 2048*64 f32
static constexpr size_t OFF_ALPHA  = OFF_V + (size_t)N_*G_*4;    // 16*2048 f32
static constexpr size_t OFF_DIS    = OFF_ALPHA + (size_t)B_*N_*4;
static constexpr size_t OFF_ROWSUM = OFF_DIS + (size_t)B_*N_*4;  // 2048 f32
static constexpr size_t OFF_ABF    = OFF_ROWSUM + 8192;          // 2048*2048 bf16
static constexpr size_t OFF_VPT    = OFF_ABF + (size_t)N_*N_*2;  // 1024*2048 bf16
static constexpr size_t OFF_S      = OFF_VPT + (size_t)(B_*G_)*N_*2; // 2048*1024 f32
static constexpr size_t OFF_PSUM   = OFF_S + (size_t)N_*(B_*G_)*4;   // 16*64*64 f32
static constexpr size_t OFF_REL    = OFF_PSUM + (size_t)B_*64*G_*4;  // 16*8*64 f32

// ---------------- K1: q = h_t @ Wq.T + bq ----------------
__global__ __launch_bounds__(64) void q_kernel(const float* __restrict__ h_t,
                                               const float* __restrict__ Wq,
                                               const float* __restrict__ bq,
                                               float* __restrict__ q) {
    int b = blockIdx.x, g = threadIdx.x;
    __shared__ float hs[H_];
    for (int i = g; i < H_; i += 64) hs[i] = h_t[b * H_ + i];
    __syncthreads();
    float acc = bq[g];
    const f32x4* wrow = (const f32x4*)(Wq + (size_t)g * H_);
    #pragma unroll 4
    for (int h4 = 0; h4 < H_ / 4; h4++) {
        f32x4 w = wrow[h4];
        f32x4 hh = *(const f32x4*)&hs[h4 * 4];
        acc = fmaf(w[0], hh[0], acc);
        acc = fmaf(w[1], hh[1], acc);
        acc = fmaf(w[2], hh[2], acc);
        acc = fmaf(w[3], hh[3], acc);
    }
    q[b * G_ + g] = acc;
}

// ---------------- K2: k,v = node_repr @ {Wk,Wv}.T + b ----------------
__global__ __launch_bounds__(64) void kv_kernel(const float* __restrict__ node_repr,
                                                const float* __restrict__ Wk,
                                                const float* __restrict__ bk,
                                                const float* __restrict__ Wv,
                                                const float* __restrict__ bv,
                                                float* __restrict__ k,
                                                float* __restrict__ v) {
    int n = blockIdx.x, g = threadIdx.x;
    __shared__ float xs[DN_];
    for (int i = g; i < DN_; i += 64) xs[i] = node_repr[(size_t)n * DN_ + i];
    __syncthreads();
    float kk = bk[g], vv = bv[g];
    const f32x4* wkr = (const f32x4*)(Wk + (size_t)g * DN_);
    const f32x4* wvr = (const f32x4*)(Wv + (size_t)g * DN_);
    #pragma unroll 4
    for (int d4 = 0; d4 < DN_ / 4; d4++) {
        f32x4 x = *(const f32x4*)&xs[d4 * 4];
        f32x4 a = wkr[d4], c = wvr[d4];
        kk = fmaf(x[0], a[0], kk); kk = fmaf(x[1], a[1], kk);
        kk = fmaf(x[2], a[2], kk); kk = fmaf(x[3], a[3], kk);
        vv = fmaf(x[0], c[0], vv); vv = fmaf(x[1], c[1], vv);
        vv = fmaf(x[2], c[2], vv); vv = fmaf(x[3], c[3], vv);
    }
    k[(size_t)n * G_ + g] = kk;
    v[(size_t)n * G_ + g] = vv;
}

// ---------------- K3: rowsum(base_adj) + bf16 cast ----------------
__global__ __launch_bounds__(256) void rowsum_cast_kernel(const float* __restrict__ base_adj,
                                                          __hip_bfloat16* __restrict__ Abf,
                                                          float* __restrict__ rowsum) {
    __shared__ float red[4];
    int n = blockIdx.x, tid = threadIdx.x;
    const f32x4* src = (const f32x4*)(base_adj + (size_t)n * N_);
    s16x4* dst = (s16x4*)(Abf + (size_t)n * N_);
    float s = 0.f;
    #pragma unroll
    for (int i = 0; i < 2; i++) {
        int m4 = tid + i * 256;
        f32x4 x = src[m4];
        s += x[0] + x[1] + x[2] + x[3];
        s16x4 o;
        o[0] = (short)f2bf(x[0]); o[1] = (short)f2bf(x[1]);
        o[2] = (short)f2bf(x[2]); o[3] = (short)f2bf(x[3]);
        dst[m4] = o;
    }
    #pragma unroll
    for (int off = 32; off; off >>= 1) s += __shfl_xor(s, off, 64);
    if ((tid & 63) == 0) red[tid >> 6] = s;
    __syncthreads();
    if (tid == 0) rowsum[n] = red[0] + red[1] + red[2] + red[3];
}

// ---------------- K4: softmax over n, alpha + d_inv_sqrt ----------------
__global__ __launch_bounds__(1024) void softmax_kernel(const float* __restrict__ q,
                                                       const float* __restrict__ k,
                                                       const float* __restrict__ rowsum,
                                                       float* __restrict__ alpha,
                                                       float* __restrict__ dis) {
    __shared__ float qs[G_];
    __shared__ float red[16];
    __shared__ float bval;
    int b = blockIdx.x, tid = threadIdx.x;
    if (tid < G_) qs[tid] = q[b * G_ + tid];
    __syncthreads();
    int n1 = tid, n2 = tid + 1024;
    float l1 = 0.f, l2 = 0.f;
    const f32x4* kr1 = (const f32x4*)(k + (size_t)n1 * G_);
    const f32x4* kr2 = (const f32x4*)(k + (size_t)n2 * G_);
    #pragma unroll 4
    for (int g4 = 0; g4 < G_ / 4; g4++) {
        f32x4 qq = *(const f32x4*)&qs[g4 * 4];
        f32x4 k1 = kr1[g4], k2 = kr2[g4];
        l1 = fmaf(qq[0], k1[0], l1); l1 = fmaf(qq[1], k1[1], l1);
        l1 = fmaf(qq[2], k1[2], l1); l1 = fmaf(qq[3], k1[3], l1);
        l2 = fmaf(qq[0], k2[0], l2); l2 = fmaf(qq[1], k2[1], l2);
        l2 = fmaf(qq[2], k2[2], l2); l2 = fmaf(qq[3], k2[3], l2);
    }
    l1 *= 0.125f; l2 *= 0.125f;
    float m = fmaxf(l1, l2);
    #pragma unroll
    for (int off = 32; off; off >>= 1) m = fmaxf(m, __shfl_xor(m, off, 64));
    if ((tid & 63) == 0) red[tid >> 6] = m;
    __syncthreads();
    if (tid < 16) {
        float x = red[tid];
        #pragma unroll
        for (int off = 8; off; off >>= 1) x = fmaxf(x, __shfl_xor(x, off, 16));
        if (tid == 0) bval = x;
    }
    __syncthreads();
    m = bval;
    __syncthreads();
    float e1 = expf(l1 - m), e2 = expf(l2 - m);
    float s = e1 + e2;
    #pragma unroll
    for (int off = 32; off; off >>= 1) s += __shfl_xor(s, off, 64);
    if ((tid & 63) == 0) red[tid >> 6] = s;
    __syncthreads();
    if (tid < 16) {
        float x = red[tid];
        #pragma unroll
        for (int off = 8; off; off >>= 1) x += __shfl_xor(x, off, 16);
        if (tid == 0) bval = x;
    }
    __syncthreads();
    float inv = 1.f / bval;
    float a1 = e1 * inv, a2 = e2 * inv;
    alpha[(size_t)b * N_ + n1] = a1;
    alpha[(size_t)b * N_ + n2] = a2;
    dis[(size_t)b * N_ + n1] = rsqrtf(fmaf(a1, rowsum[n1], 1.f + 1e-8f));
    dis[(size_t)b * N_ + n2] = rsqrtf(fmaf(a2, rowsum[n2], 1.f + 1e-8f));
}

// ---------------- K5: VpT[c][m] = bf16(dis[b,m]*v[m,g]), c=b*64+g (LDS transpose) ----
__global__ __launch_bounds__(256) void vpt_kernel(const float* __restrict__ v,
                                                  const float* __restrict__ dis,
                                                  __hip_bfloat16* __restrict__ VpT) {
    __shared__ float vs[64][65];
    __shared__ float dsv[64];
    const int b = blockIdx.y;
    const int m0 = blockIdx.x * 64;
    const int tid = threadIdx.x;
    const int g = tid & 63, r = tid >> 6;
    #pragma unroll
    for (int i = 0; i < 16; i++) {
        int m = r + i * 4;
        vs[m][g] = v[(size_t)(m0 + m) * G_ + g];
    }
    if (tid < 64) dsv[tid] = dis[(size_t)b * N_ + m0 + tid];
    __syncthreads();
    const int lane = tid & 63, gbase = tid >> 6;
    #pragma unroll
    for (int j = 0; j < 16; j++) {
        int gg = gbase * 16 + j;
        float val = dsv[lane] * vs[lane][gg];
        *(unsigned short*)&VpT[((size_t)b * G_ + gg) * N_ + m0 + lane] = f2bf(val);
    }
}

// ---------------- K6: S = Abf @ VpT^T   (MFMA bf16, gl_lds staging) ----------------
#define BM 128
#define BN 64
#define BK 32
__global__ __launch_bounds__(256) void gemm_S(const __hip_bfloat16* __restrict__ Abf,
                                              const __hip_bfloat16* __restrict__ VpT,
                                              float* __restrict__ S) {
    __shared__ __align__(16) short A_lds[BM * BK]; // [row][k] linear
    __shared__ __align__(16) short B_lds[BN * BK]; // [col][k] linear
    const int tid = threadIdx.x;
    const int n0 = blockIdx.x * BM;
    const int c0 = blockIdx.y * BN;
    const int wave = tid >> 6, l = tid & 63;
    const int wr = wave >> 1, wc = wave & 1;
    const int lr = l & 15, kg = l >> 4;
    const int srow = l >> 2, skc = (l & 3) << 3;

    f32x4 acc[4][2];
    #pragma unroll
    for (int m = 0; m < 4; m++)
        #pragma unroll
        for (int n = 0; n < 2; n++) acc[m][n] = (f32x4){0.f, 0.f, 0.f, 0.f};

    // per-wave staging: wave w loads A rows [w*32, w*32+32), B rows [w*16, w*16+16)
    const __hip_bfloat16* agp0 = Abf + (size_t)(n0 + wave * 32 + srow) * N_ + skc;
    const __hip_bfloat16* agp1 = agp0 + (size_t)16 * N_;
    const __hip_bfloat16* bgp  = VpT + (size_t)(c0 + wave * 16 + srow) * N_ + skc;
    short* alp0 = &A_lds[(wave * 32) * BK];
    short* alp1 = &A_lds[(wave * 32 + 16) * BK];
    short* blp  = &B_lds[(wave * 16) * BK];

    for (int k0 = 0; k0 < N_; k0 += BK) {
        gl_lds16(agp0 + k0, alp0);
        gl_lds16(agp1 + k0, alp1);
        gl_lds16(bgp + k0, blp);
        __syncthreads();   // drains vmcnt before barrier (compiler-inserted)

        short8 a[4], bfr[2];
        #pragma unroll
        for (int m = 0; m < 4; m++)
            a[m] = *(const short8*)&A_lds[(wr * 64 + m * 16 + lr) * BK + kg * 8];
        #pragma unroll
        for (int n = 0; n < 2; n++)
            bfr[n] = *(const short8*)&B_lds[(wc * 32 + n * 16 + lr) * BK + kg * 8];
        #pragma unroll
        for (int m = 0; m < 4; m++)
            #pragma unroll
            for (int n = 0; n < 2; n++)
                acc[m][n] = __builtin_amdgcn_mfma_f32_16x16x32_bf16(a[m], bfr[n], acc[m][n], 0, 0, 0);
        __syncthreads();
    }
    // C/D layout: col=lane&15, row=(lane>>4)*4+reg
    #pragma unroll
    for (int m = 0; m < 4; m++)
        #pragma unroll
        for (int n = 0; n < 2; n++)
            #pragma unroll
            for (int r = 0; r < 4; r++) {
                int row = n0 + wr * 64 + m * 16 + kg * 4 + r;
                int col = c0 + wc * 32 + n * 16 + lr;
                S[(size_t)row * (B_ * G_) + col] = acc[m][n][r];
            }
}

// ---------------- K7: z -> Wo -> ReLU -> LN -> un  (+ fused summary partials) -------
__global__ __launch_bounds__(256) void epilogue_kernel(const float* __restrict__ S,
                                                       const float* __restrict__ v,
                                                       const float* __restrict__ alpha,
                                                       const float* __restrict__ dis,
                                                       const float* __restrict__ Wo,
                                                       const float* __restrict__ bo,
                                                       const float* __restrict__ gamma,
                                                       const float* __restrict__ beta,
                                                       float* __restrict__ un,
                                                       float* __restrict__ psum_part) {
    __shared__ float WoT[G_ * G_];   // WoT[g][g2] = Wo[g2][g]
    __shared__ float zbuf[4][G_];
    __shared__ float cvec[3 * G_];   // bo, gamma, beta
    const int tid = threadIdx.x;
    const int b = blockIdx.y;
    const int nbase = blockIdx.x * 32;
    for (int i = tid; i < G_ * G_; i += 256) {
        int g = i >> 6, g2 = i & 63;
        WoT[i] = Wo[g2 * G_ + g];
    }
    if (tid < G_) {
        cvec[tid] = bo[tid];
        cvec[G_ + tid] = gamma[tid];
        cvec[2 * G_ + tid] = beta[tid];
    }
    __syncthreads();
    const int wave = tid >> 6, lane = tid & 63;
    float psum = 0.f;
    for (int i = 0; i < 8; i++) {
        int n = nbase + i * 4 + wave;
        float al = alpha[(size_t)b * N_ + n];
        float di = dis[(size_t)b * N_ + n];
        float zp = di * fmaf(al, S[(size_t)n * (B_ * G_) + b * G_ + lane],
                             di * v[(size_t)n * G_ + lane]);
        zbuf[wave][lane] = zp;
        __syncthreads();
        float y = cvec[lane];
        #pragma unroll
        for (int g = 0; g < G_; g++) y = fmaf(zbuf[wave][g], WoT[g * G_ + lane], y);
        y = fmaxf(y, 0.f);
        float s = y;
        #pragma unroll
        for (int off = 32; off; off >>= 1) s += __shfl_xor(s, off, 64);
        float mu = s * (1.f / 64.f);
        float d0 = y - mu;
        float s2 = d0 * d0;
        #pragma unroll
        for (int off = 32; off; off >>= 1) s2 += __shfl_xor(s2, off, 64);
        float rstd = rsqrtf(s2 * (1.f / 64.f) + 1e-5f);
        float outv = fmaf(d0 * rstd, cvec[G_ + lane], cvec[2 * G_ + lane]);
        un[((size_t)b * N_ + n) * G_ + lane] = outv;
        psum = fmaf(al, outv, psum);
        __syncthreads();
    }
    // reduce psum across the 4 waves -> one partial per (b, block)
    zbuf[wave][lane] = psum;
    __syncthreads();
    if (tid < G_) {
        float s = zbuf[0][tid] + zbuf[1][tid] + zbuf[2][tid] + zbuf[3][tid];
        psum_part[((size_t)b * 64 + blockIdx.x) * G_ + tid] = s;
    }
}

// ---------------- K8: relation_vector partials ----------------
__global__ __launch_bounds__(256) void rel_kernel(const float* __restrict__ alpha,
                                                  const float* __restrict__ v,
                                                  float* __restrict__ rel_part) {
    __shared__ float part[256];
    const int b = blockIdx.x, chunk = blockIdx.y;
    const int g = threadIdx.x & 63, c = threadIdx.x >> 6;
    float acc = 0.f;
    const int nend = chunk * 256 + 256;
    for (int n = chunk * 256 + c; n < nend; n += 4)
        acc = fmaf(alpha[(size_t)b * N_ + n], v[(size_t)n * G_ + g], acc);
    part[threadIdx.x] = acc;
    __syncthreads();
    if (c == 0)
        rel_part[((size_t)b * 8 + chunk) * G_ + g] =
            part[g] + part[64 + g] + part[128 + g] + part[192 + g];
}

// ---------------- K9: final reduce of both summaries ----------------
__global__ __launch_bounds__(64) void reduce_kernel(const float* __restrict__ psum_part,
                                                    const float* __restrict__ rel_part,
                                                    float* __restrict__ out) {
    const int b = blockIdx.x, g = threadIdx.x;
    float s = 0.f;
    for (int c = 0; c < 64; c++) s += psum_part[((size_t)b * 64 + c) * G_ + g];
    out[b * G_ + g] = s;                       // propagated_summary
    float r = 0.f;
    for (int c = 0; c < 8; c++) r += rel_part[((size_t)b * 8 + c) * G_ + g];
    out[1024 + b * G_ + g] = r;                // relation_vector
}

extern "C" void kernel_launch(void* const* d_in, const int* in_sizes, int n_in,
                              void* d_out, int out_size, void* d_ws, size_t ws_size,
                              hipStream_t stream) {
    const float* h_t       = (const float*)d_in[0];
    const float* node_repr = (const float*)d_in[1];
    const float* base_adj  = (const float*)d_in[2];
    const float* Wq    = (const float*)d_in[3];
    const float* bq    = (const float*)d_in[4];
    const float* Wk    = (const float*)d_in[5];
    const float* bk    = (const float*)d_in[6];
    const float* Wv    = (const float*)d_in[7];
    const float* bv    = (const float*)d_in[8];
    const float* Wo    = (const float*)d_in[9];
    const float* bo    = (const float*)d_in[10];
    const float* gamma = (const float*)d_in[11];
    const float* beta  = (const float*)d_in[12];
    float* out = (float*)d_out;

    char* ws = (char*)d_ws;
    float* q      = (float*)(ws + OFF_Q);
    float* k      = (float*)(ws + OFF_K);
    float* v      = (float*)(ws + OFF_V);
    float* alpha  = (float*)(ws + OFF_ALPHA);
    float* dis    = (float*)(ws + OFF_DIS);
    float* rowsum = (float*)(ws + OFF_ROWSUM);
    __hip_bfloat16* Abf = (__hip_bfloat16*)(ws + OFF_ABF);
    __hip_bfloat16* VpT = (__hip_bfloat16*)(ws + OFF_VPT);
    float* S      = (float*)(ws + OFF_S);
    float* psum_part = (float*)(ws + OFF_PSUM);
    float* rel_part  = (float*)(ws + OFF_REL);

    float* un = out + 2048; // updated_nodes region

    q_kernel<<<B_, 64, 0, stream>>>(h_t, Wq, bq, q);
    kv_kernel<<<N_, 64, 0, stream>>>(node_repr, Wk, bk, Wv, bv, k, v);
    rowsum_cast_kernel<<<N_, 256, 0, stream>>>(base_adj, Abf, rowsum);
    softmax_kernel<<<B_, 1024, 0, stream>>>(q, k, rowsum, alpha, dis);
    vpt_kernel<<<dim3(N_ / 64, B_), 256, 0, stream>>>(v, dis, VpT);
    rel_kernel<<<dim3(B_, 8), 256, 0, stream>>>(alpha, v, rel_part);
    gemm_S<<<dim3(N_ / BM, (B_ * G_) / BN), 256, 0, stream>>>(Abf, VpT, S);
    epilogue_kernel<<<dim3(N_ / 32, B_), 256, 0, stream>>>(S, v, alpha, dis, Wo, bo, gamma, beta, un, psum_part);
    reduce_kernel<<<B_, 64, 0, stream>>>(psum_part, rel_part, out);
}